// Round 5
// baseline (332.139 us; speedup 1.0000x reference)
//
#include <hip/hip_runtime.h>
#include <hip/hip_bf16.h>
#include <stdint.h>

// Problem constants (fixed by the reference file)
#define NB 8     // batch
#define NS 2048  // sequence
#define ND 1536  // model dim (K)
#define NT 2048  // padded tracks (N)
#define NH 8     // heads
#define NK1 (ND / 32)  // 48 K-iterations at BK=32

// NUM_TRACKS = [128,256,512,1024,2048,64,32,1024] -> ceil(nt/128) (in 128-tiles)
__constant__ int c_tiles[NH] = {1, 2, 4, 8, 16, 1, 1, 8};

typedef short bf16x8 __attribute__((ext_vector_type(8)));  // 8 bf16 (4 VGPRs)
typedef unsigned short u16x8 __attribute__((ext_vector_type(8)));
typedef float f32x4 __attribute__((ext_vector_type(4)));

__device__ __forceinline__ unsigned short f2bf(float f) {
    union { float f; unsigned u; } a; a.f = f;
    unsigned r = a.u + 0x7fffu + ((a.u >> 16) & 1u);  // RNE
    return (unsigned short)(r >> 16);
}

// ---------------- Fused prepass: x fp32->bf16  +  W transpose+convert -------
#define XBLK 24576
__global__ void cvt_kernel(const float* __restrict__ x,
                           const float* __restrict__ W,
                           const int* __restrict__ hidx,
                           unsigned short* __restrict__ xb,
                           unsigned short* __restrict__ Wt) {
    const int bid = blockIdx.x;
    const int tid = threadIdx.x;
    if (bid < XBLK) {
        const size_t i = (size_t)bid * 256 + tid;  // float4 index
        float4 v = ((const float4*)x)[i];
        ushort4 o;
        o.x = f2bf(v.x); o.y = f2bf(v.y); o.z = f2bf(v.z); o.w = f2bf(v.w);
        ((ushort4*)xb)[i] = o;
        return;
    }
    // W transpose: wid -> (t-tile 32, d-tile 24, h 8)
    const int wid = bid - XBLK;
    const int h = wid / (32 * 24);
    const int rem = wid % (32 * 24);
    const int t0 = (rem % 32) * 64;
    const int d0 = (rem / 32) * 64;
    bool used = false;
    for (int i = 0; i < NB; ++i) used |= (hidx[i] == h);
    if (!used || t0 >= c_tiles[h] * 128) return;

    __shared__ float tile[64][69];  // [d][t], padded
#pragma unroll
    for (int i = 0; i < 4; ++i) {
        const int idx = tid + i * 256;  // 1024 float4 chunks
        const int d = idx >> 4, c = (idx & 15) * 4;
        float4 v = *(const float4*)&W[((size_t)h * ND + d0 + d) * NT + t0 + c];
        tile[d][c] = v.x; tile[d][c + 1] = v.y;
        tile[d][c + 2] = v.z; tile[d][c + 3] = v.w;
    }
    __syncthreads();
    const int t = tid >> 2, dc = (tid & 3) * 16;  // 16 bf16 = 32 B per thread
    u16x8 o0, o1;
#pragma unroll
    for (int j = 0; j < 8; ++j) o0[j] = f2bf(tile[dc + j][t]);
#pragma unroll
    for (int j = 0; j < 8; ++j) o1[j] = f2bf(tile[dc + 8 + j][t]);
    unsigned short* p = Wt + ((size_t)h * NT + t0 + t) * ND + d0 + dc;
    *(u16x8*)p = o0;
    *(u16x8*)(p + 8) = o1;
}

// ---------------- GEMM: out[b] = x[b] @ W[h(b)] + bias[h(b)] ----------------
// 256x128 tile (8 waves), BK=32, DOUBLE-BUFFERED GLDS (A and B), 1 barrier
// per iter: GLDS(k+1) issued after barrier(k) -> in flight across the whole
// compute(k), drained at barrier(k+1). LDS = 2*(16+8) = 48 KB -> 3 blocks/CU.
// XOR bank swizzle: LDS slot (r, sc) holds global k-chunk gc = sc ^ (r&3).
#define GLDS(g, l)                                                      \
    __builtin_amdgcn_global_load_lds(                                   \
        (const __attribute__((address_space(1))) void*)(g),             \
        (__attribute__((address_space(3))) void*)(l), 16, 0, 0)

__global__ __launch_bounds__(512) void gemm_kernel(
    const unsigned short* __restrict__ xb,   // bf16 [NB][NS][ND]
    const unsigned short* __restrict__ wt,   // bf16 [NH][NT][ND]
    const float* __restrict__ bias,          // fp32 [NH][NT]
    const int* __restrict__ hidx,            // [NB]
    float* __restrict__ out)                 // fp32 [NB][NS][NT]
{
    const int tid = threadIdx.x;
    const int id = blockIdx.x;

    int hh[NB], tl[NB];
    int P = 0;
#pragma unroll
    for (int b = 0; b < NB; ++b) {
        hh[b] = hidx[b];
        tl[b] = c_tiles[hh[b]];
        P += tl[b];
    }
    const int C = 8 * P;

    int batch, m0, n0;
    if (id >= C) {
        // ---- zero tile: 256x128 of exact zeros ----
        const int Pz = 128 - P;
        const int z = id - C;
        int p = z % Pz;
        const int m = z / Pz;
        int b = 0;
        while (p >= 16 - tl[b]) { p -= 16 - tl[b]; ++b; }
        batch = b; n0 = (tl[b] + p) * 128; m0 = m * 256;
        float* outb = out + (size_t)batch * NS * NT;
        const int row = tid >> 1;
        const int c0 = (tid & 1) * 64;
        float4 zv = make_float4(0.f, 0.f, 0.f, 0.f);
        float4* ptr = (float4*)(outb + (size_t)(m0 + row) * NT + (n0 + c0));
#pragma unroll
        for (int j = 0; j < 16; ++j) ptr[j] = zv;
        return;
    }
    {
        int p = id % P;
        const int m = id / P;
        int b = 0;
        while (p >= tl[b]) { p -= tl[b]; ++b; }
        batch = b; n0 = p * 128; m0 = m * 256;
    }
    const int h = hh[batch];
    float* outb = out + (size_t)batch * NS * NT;

    __shared__ unsigned short As[2][256 * 32];  // 2 x 16 KB, swizzled
    __shared__ unsigned short Bs[2][128 * 32];  // 2 x  8 KB, swizzled

    const int lane = tid & 63;
    const int wave = tid >> 6;
    const int wm = (wave >> 1) * 64;   // 4 m-waves over 256 rows
    const int wn = (wave & 1) * 64;    // 2 n-waves over 128 cols
    const int fr = lane & 15;
    const int q = lane >> 4;           // k-group 0..3

    // Staging: A = 1024 16B chunks (2/thread), B = 512 (1/thread).
    // Chunk c: row r = c>>2, slot sc = c&3, holds global k-chunk gc = sc^(r&3).
    const unsigned short* ga[2];
    int laoff[2];
#pragma unroll
    for (int j = 0; j < 2; ++j) {
        const int c = tid + 512 * j;
        const int r = c >> 2, gc = (c & 3) ^ (r & 3);
        ga[j] = xb + ((size_t)batch * NS + m0 + r) * ND + gc * 8;
        laoff[j] = c * 8;
    }
    const unsigned short* gb;
    int lboff;
    {
        const int c = tid;
        const int r = c >> 2, gc = (c & 3) ^ (r & 3);
        gb = wt + ((size_t)h * NT + n0 + r) * ND + gc * 8;
        lboff = c * 8;
    }

    // Reader-side swizzled k-offset (in shorts): sc = q ^ (fr&3), row*32.
    const int sw = (q ^ (fr & 3)) * 8;

    f32x4 acc[4][4] = {};

    // Preload tile 0 into buffer 0.
    GLDS(ga[0], &As[0][laoff[0]]);
    GLDS(ga[1], &As[0][laoff[1]]);
    GLDS(gb, &Bs[0][lboff]);
    ga[0] += 32; ga[1] += 32; gb += 32;

    for (int it = 0; it < NK1; ++it) {
        const int cur = it & 1;
        __syncthreads();  // buffer `cur` ready (compiler drains vmcnt here)
        if (it + 1 < NK1) {
            const int nxt = cur ^ 1;
            GLDS(ga[0], &As[nxt][laoff[0]]);
            GLDS(ga[1], &As[nxt][laoff[1]]);
            GLDS(gb, &Bs[nxt][lboff]);
            ga[0] += 32; ga[1] += 32; gb += 32;
        }
        bf16x8 af[4], bfr[4];
#pragma unroll
        for (int mi = 0; mi < 4; ++mi)
            af[mi] = *(const bf16x8*)(&As[cur][(wm + mi * 16 + fr) * 32 + sw]);
#pragma unroll
        for (int ni = 0; ni < 4; ++ni)
            bfr[ni] = *(const bf16x8*)(&Bs[cur][(wn + ni * 16 + fr) * 32 + sw]);
#pragma unroll
        for (int mi = 0; mi < 4; ++mi)
#pragma unroll
            for (int ni = 0; ni < 4; ++ni)
                acc[mi][ni] = __builtin_amdgcn_mfma_f32_16x16x32_bf16(
                    af[mi], bfr[ni], acc[mi][ni], 0, 0, 0);
    }

    // Epilogue: C/D layout col=lane&15, row=(lane>>4)*4+reg
    float bv[4];
#pragma unroll
    for (int ni = 0; ni < 4; ++ni)
        bv[ni] = bias[(size_t)h * NT + n0 + wn + ni * 16 + fr];

    const int rbase = m0 + wm + q * 4;
#pragma unroll
    for (int mi = 0; mi < 4; ++mi) {
#pragma unroll
        for (int r = 0; r < 4; ++r) {
            float* op = outb + (size_t)(rbase + mi * 16 + r) * NT + n0 + wn + fr;
#pragma unroll
            for (int ni = 0; ni < 4; ++ni)
                op[ni * 16] = acc[mi][ni][r] + bv[ni];
        }
    }
}

extern "C" void kernel_launch(void* const* d_in, const int* in_sizes, int n_in,
                              void* d_out, int out_size, void* d_ws, size_t ws_size,
                              hipStream_t stream) {
    const float* x    = (const float*)d_in[0];  // [NB][NS][ND] fp32
    const int*   hidx = (const int*)d_in[1];    // [NB] int32
    const float* W    = (const float*)d_in[2];  // [NH][ND][NT] fp32
    const float* bias = (const float*)d_in[3];  // [NH][NT] fp32
    float* out = (float*)d_out;

    unsigned short* xb = (unsigned short*)d_ws;            // 48 MiB bf16 x
    unsigned short* wt = xb + (size_t)NB * NS * ND;        // 48 MiB bf16 W^T

    // Fused convert: 24576 x-blocks + 6144 W-blocks
    cvt_kernel<<<dim3(XBLK + 32 * 24 * NH), dim3(256), 0, stream>>>(
        x, W, hidx, xb, wt);
    // GEMM: 1024 blocks = 8 m-tiles x 16 n-tiles x 8 batches, balanced decode
    gemm_kernel<<<dim3(1024), dim3(512), 0, stream>>>(xb, wt, bias, hidx, out);
}